// Round 7
// baseline (124.386 us; speedup 1.0000x reference)
//
#include <hip/hip_runtime.h>
#include <hip/hip_bf16.h>
#include <stdint.h>
#include <stddef.h>

// MMD via single signed 2N x 2N RBF gram, lower triangle only.
// Round 14: perfect load balance — ONE 128x128 tile per block, grid = 8256
// identical blocks (8 refill rounds of the ~1024 co-resident slots; r13's
// 1.9-round grid left the tail at 1-2 waves/SIMD -> avg occupancy 30%).
// Full 32 KB B-tile staged once -> single barrier, no double buffer.
// Tile computed in two 64-col halves so acc[2][4] = 32 AGPRs (reg rule:
// arch+AGPR <= 512/(waves/SIMD); ~112 < 128 @ 4 blk/CU, 16 waves/CU).
// 8256 blocks atomicAdd into 64 hashed partials; 1-block finish kernel sums.

#define N_PTS   8192
#define DIM     256
#define TWO_N   16384
#define NTILE   8256      // 128*129/2 lower-triangle tiles

#define AS1 __attribute__((address_space(1)))
#define AS3 __attribute__((address_space(3)))

typedef __attribute__((ext_vector_type(4))) float f32x4;
typedef __attribute__((ext_vector_type(4))) int   i32x4;
typedef __attribute__((ext_vector_type(8))) int   i32x8;

// ---------------------------------------------------------------------------
// Prep: fp32 -> fp8 e4m3 (row-major) + c2-scaled fp32 row norms; zero partials.
// n2[row] = c2 * |z_row|^2, c2 = -log2e/sigma (epilogue adds directly).
// ---------------------------------------------------------------------------
__global__ __launch_bounds__(256) void mmd_prep(const float* __restrict__ X,
                                                const float* __restrict__ Y,
                                                const int* __restrict__ sigmap,
                                                unsigned char* __restrict__ Zf8,
                                                float* __restrict__ n2,
                                                float* __restrict__ part) {
    if (blockIdx.x == 0 && threadIdx.x < 64) part[threadIdx.x] = 0.0f;

    const int wave = threadIdx.x >> 6;
    const int lane = threadIdx.x & 63;
    const int row  = blockIdx.x * 4 + wave;          // 0 .. TWO_N-1

    const float* src = (row < N_PTS) ? (X + (size_t)row * DIM)
                                     : (Y + (size_t)(row - N_PTS) * DIM);
    float4 v = ((const float4*)src)[lane];           // 64 lanes x 4 = 256

    float s = v.x * v.x + v.y * v.y + v.z * v.z + v.w * v.w;
#pragma unroll
    for (int off = 32; off; off >>= 1) s += __shfl_down(s, off, 64);
    if (lane == 0) {
        const float c2 = -1.4426950408889634f / (float)(*sigmap);
        n2[row] = c2 * s;
    }

    const int p01 = __builtin_amdgcn_cvt_pk_fp8_f32(v.x, v.y, 0, false);
    const int p23 = __builtin_amdgcn_cvt_pk_fp8_f32(v.z, v.w, 0, false);
    const unsigned int pk = ((unsigned)p01 & 0xffffu) | ((unsigned)p23 << 16);
    *(unsigned int*)(Zf8 + (size_t)row * DIM + (size_t)lane * 4) = pk;
}

// ---------------------------------------------------------------------------
// Main. grid = NTILE; bid -> (br, cc) by triangular inversion, cc <= br.
// 4 waves in 4x1; wave owns rows wave*32..+32 of the 128-row panel.
// Stage full 128-col x 256B B-tile (32 KB) once; ONE barrier; compute two
// 64-col halves (16 MFMA 16x16x128 MX-fp8 + epilogue each; acc reused).
// LDS col row = 256 B = 16 x 16B slots; slot s holds global chunk s^(c&15).
// ---------------------------------------------------------------------------
__global__ __launch_bounds__(256, 4) void mmd_main(const unsigned char* __restrict__ Zf8,
                                                   const float* __restrict__ n2,
                                                   const int* __restrict__ sigmap,
                                                   float* __restrict__ part) {
    __shared__ char smem_b[32768];   // full B-tile: 128 cols x 256 B
    __shared__ float wsum[4];

    const int r = (int)blockIdx.x;
    int k = (int)((__builtin_sqrt(8.0 * (double)r + 1.0) - 1.0) * 0.5);
    int base = (k * (k + 1)) >> 1;
    if (r < base)                { --k; base = (k * (k + 1)) >> 1; }
    else if (r >= base + k + 1)  { ++k; base = (k * (k + 1)) >> 1; }
    const int br = k;                // row-tile 0..127
    const int cc = r - base;         // col-tile 0..br

    const int t    = threadIdx.x;
    const int wave = t >> 6;         // 0..3: 32-row group
    const int lane = t & 63;
    const int g    = lane >> 4;      // k-quad
    const int ml   = lane & 15;
    const int rowBase = br * 128;

    const float m2 = 2.8853900817779268f / (float)(*sigmap);   // 2*log2e/sigma
    const int   SC = 0x7f7f7f7f;     // E8M0 unit scales (2^0)

    // ---- stage full B-tile: 2048 16B chunks / 256 threads = 8 per thread
    // col = i*16 + (t>>4); slot s = t&15; source chunk = s ^ (col&15)
    {
        const int gbase = (t >> 4) * 256 + (((t & 15) ^ ((t >> 4) & 15)) * 16);
        const unsigned char* sb = Zf8 + (size_t)cc * 32768 + gbase;
        const int lbase = t * 16;
#pragma unroll
        for (int i = 0; i < 8; ++i)
            __builtin_amdgcn_global_load_lds((const AS1 void*)(sb + i * 4096),
                                             (AS3 void*)(smem_b + i * 4096 + lbase), 16, 0, 0);
    }

    // ---- A fragments (full K, this wave's 32 rows): 32 VGPRs ----
    i32x8 af[2][2];
#pragma unroll
    for (int mt = 0; mt < 2; ++mt) {
        const unsigned char* rp =
            Zf8 + (size_t)(rowBase + wave * 32 + mt * 16 + ml) * 256 + g * 32;
#pragma unroll
        for (int kc = 0; kc < 2; ++kc) {
            union { i32x4 h[2]; i32x8 v; } u;
            u.h[0] = *(const i32x4*)(rp + kc * 128);
            u.h[1] = *(const i32x4*)(rp + kc * 128 + 16);
            af[mt][kc] = u.v;
        }
    }
    // row-norm coefficients for this lane's 8 C rows
    float a_i[2][4];
#pragma unroll
    for (int mt = 0; mt < 2; ++mt)
#pragma unroll
        for (int rr = 0; rr < 4; ++rr)
            a_i[mt][rr] = n2[rowBase + wave * 32 + mt * 16 + g * 4 + rr];

    // column factors for all 8 col groups
    float eb[8];
#pragma unroll
    for (int j = 0; j < 8; ++j)
        eb[j] = __builtin_amdgcn_exp2f(n2[cc * 128 + j * 16 + ml]);

    // bf ds_read bases (col component = ml*256; chunk j = kc*8 + g*2 (+1))
    int rb0[2], rb1[2];
#pragma unroll
    for (int kc = 0; kc < 2; ++kc) {
        rb0[kc] = ml * 256 + (((kc * 8 + g * 2)     ^ ml) * 16);
        rb1[kc] = ml * 256 + (((kc * 8 + g * 2 + 1) ^ ml) * 16);
    }

    const f32x4 zacc = {0.0f, 0.0f, 0.0f, 0.0f};

    __syncthreads();                 // B-tile staged (single barrier)

    float ts0 = 0.0f, ts1 = 0.0f, ts2 = 0.0f, ts3 = 0.0f;
#pragma unroll
    for (int h = 0; h < 2; ++h) {    // two 64-col halves; acc reused
        f32x4 acc[2][4];
#pragma unroll
        for (int nt = 0; nt < 4; ++nt) {
#pragma unroll
            for (int kc = 0; kc < 2; ++kc) {
                union { i32x4 hh[2]; i32x8 v; } u;
                u.hh[0] = *(const i32x4*)(smem_b + h * 16384 + nt * 4096 + rb0[kc]);
                u.hh[1] = *(const i32x4*)(smem_b + h * 16384 + nt * 4096 + rb1[kc]);
                const i32x8 bf = u.v;
#pragma unroll
                for (int mt = 0; mt < 2; ++mt)
                    acc[mt][nt] = __builtin_amdgcn_mfma_scale_f32_16x16x128_f8f6f4(
                        af[mt][kc], bf, (kc == 0) ? zacc : acc[mt][nt],
                        0, 0, 0, SC, 0, SC);
            }
        }
        // epilogue for this half
#pragma unroll
        for (int mt = 0; mt < 2; ++mt)
#pragma unroll
            for (int nt = 0; nt < 4; ++nt) {
                const float e = eb[h * 4 + nt];
                ts0 = fmaf(__builtin_amdgcn_exp2f(fmaf(acc[mt][nt][0], m2, a_i[mt][0])), e, ts0);
                ts1 = fmaf(__builtin_amdgcn_exp2f(fmaf(acc[mt][nt][1], m2, a_i[mt][1])), e, ts1);
                ts2 = fmaf(__builtin_amdgcn_exp2f(fmaf(acc[mt][nt][2], m2, a_i[mt][2])), e, ts2);
                ts3 = fmaf(__builtin_amdgcn_exp2f(fmaf(acc[mt][nt][3], m2, a_i[mt][3])), e, ts3);
            }
    }

    // symmetry weight and sign for this tile
    const float sgn = ((cc < 64) == (br < 64)) ? 1.0f : -1.0f;
    const float w   = (cc == br) ? sgn : 2.0f * sgn;
    float s = w * ((ts0 + ts1) + (ts2 + ts3));

    // ---- block reduction + hashed atomic ----
#pragma unroll
    for (int off = 32; off; off >>= 1) s += __shfl_down(s, off, 64);
    if (lane == 0) wsum[wave] = s;
    __syncthreads();
    if (t == 0)
        atomicAdd(part + (r & 63), wsum[0] + wsum[1] + wsum[2] + wsum[3]);
}

// ---------------------------------------------------------------------------
// Finish: reduce 64 partials, scale, write scalar output.
// ---------------------------------------------------------------------------
__global__ __launch_bounds__(64) void mmd_finish(const float* __restrict__ part,
                                                 float* __restrict__ out) {
    const int lane = threadIdx.x & 63;
    float s = part[lane];
#pragma unroll
    for (int off = 32; off; off >>= 1) s += __shfl_down(s, off, 64);
    if (lane == 0) out[0] = s * (1.0f / 67108864.0f);
}

// ---------------------------------------------------------------------------
extern "C" void kernel_launch(void* const* d_in, const int* in_sizes, int n_in,
                              void* d_out, int out_size, void* d_ws, size_t ws_size,
                              hipStream_t stream) {
    const float* X      = (const float*)d_in[0];
    const float* Y      = (const float*)d_in[1];
    const int*   sigmap = (const int*)d_in[2];
    float*       out    = (float*)d_out;

    unsigned char* Zf8  = (unsigned char*)d_ws;                       // 4 MB
    float*         n2   = (float*)((char*)d_ws + (size_t)TWO_N * DIM);
    float*         part = n2 + TWO_N;                                 // 64 floats

    mmd_prep<<<TWO_N / 4, 256, 0, stream>>>(X, Y, sigmap, Zf8, n2, part);
    mmd_main<<<NTILE, 256, 0, stream>>>(Zf8, n2, sigmap, part);
    mmd_finish<<<1, 64, 0, stream>>>(part, out);
}

// Round 8
// 114.062 us; speedup vs baseline: 1.0905x; 1.0905x over previous
//
#include <hip/hip_runtime.h>
#include <hip/hip_bf16.h>
#include <stdint.h>
#include <stddef.h>

// MMD via single signed 2N x 2N RBF gram, lower triangle only.
// Round 15: row-pairing for perfect balance at r13 amortization.
// Block (p, cc) handles rows {p, 127-p}, cols ≡ cc (mod 16): tile counts
// nT(p,cc)+nT(127-p,cc) are constant ±1 -> grid = 64*16 = 1024 equal blocks
// = exactly one residency round (4 blk/CU x 256 CU), no refill, no tail.
// Per block: r13's slice pipeline (64-col x K=256 16 KB slices, double-
// buffered, stage-next || compute-current, 1 barrier/slice); A-panel regs
// reload once at the row switch. acc[2][4]=32 AGPR, arch ~64 -> 4 waves/SIMD.
// 1024 blocks atomicAdd into 64 hashed partials; finish kernel reduces.

#define N_PTS   8192
#define DIM     256
#define TWO_N   16384

#define AS1 __attribute__((address_space(1)))
#define AS3 __attribute__((address_space(3)))

typedef __attribute__((ext_vector_type(4))) float f32x4;
typedef __attribute__((ext_vector_type(4))) int   i32x4;
typedef __attribute__((ext_vector_type(8))) int   i32x8;

// ---------------------------------------------------------------------------
// Prep: fp32 -> fp8 e4m3 (row-major) + c2-scaled fp32 row norms; zero partials.
// n2[row] = c2 * |z_row|^2, c2 = -log2e/sigma (epilogue adds directly).
// ---------------------------------------------------------------------------
__global__ __launch_bounds__(256) void mmd_prep(const float* __restrict__ X,
                                                const float* __restrict__ Y,
                                                const int* __restrict__ sigmap,
                                                unsigned char* __restrict__ Zf8,
                                                float* __restrict__ n2,
                                                float* __restrict__ part) {
    if (blockIdx.x == 0 && threadIdx.x < 64) part[threadIdx.x] = 0.0f;

    const int wave = threadIdx.x >> 6;
    const int lane = threadIdx.x & 63;
    const int row  = blockIdx.x * 4 + wave;          // 0 .. TWO_N-1

    const float* src = (row < N_PTS) ? (X + (size_t)row * DIM)
                                     : (Y + (size_t)(row - N_PTS) * DIM);
    float4 v = ((const float4*)src)[lane];           // 64 lanes x 4 = 256

    float s = v.x * v.x + v.y * v.y + v.z * v.z + v.w * v.w;
#pragma unroll
    for (int off = 32; off; off >>= 1) s += __shfl_down(s, off, 64);
    if (lane == 0) {
        const float c2 = -1.4426950408889634f / (float)(*sigmap);
        n2[row] = c2 * s;
    }

    const int p01 = __builtin_amdgcn_cvt_pk_fp8_f32(v.x, v.y, 0, false);
    const int p23 = __builtin_amdgcn_cvt_pk_fp8_f32(v.z, v.w, 0, false);
    const unsigned int pk = ((unsigned)p01 & 0xffffu) | ((unsigned)p23 << 16);
    *(unsigned int*)(Zf8 + (size_t)row * DIM + (size_t)lane * 4) = pk;
}

// ---------------------------------------------------------------------------
// Main. grid = 1024: p = bid>>4 (row pair {p, 127-p}), cc = bid&15.
// Slices: for each owned row r, tiles bc = cc, cc+16, .. <= r; 2 col-slices
// (h=0,1: cols bc*128+h*64 .. +64, full K=256) per tile. 4 waves in 4x1;
// wave owns rows r*128 + wave*32 .. +32. Per slice: [barrier][stage next]
// [16 MFMA 16x16x128 MX-fp8][epilogue]. LDS col = 256 B = 16 x 16B slots,
// slot s of col c holds global chunk s ^ (c&15).
// ---------------------------------------------------------------------------
__global__ __launch_bounds__(256, 4) void mmd_main(const unsigned char* __restrict__ Zf8,
                                                   const float* __restrict__ n2,
                                                   const int* __restrict__ sigmap,
                                                   float* __restrict__ part) {
    __shared__ char smem_b[32768];   // 2 x 16 KB col-slice buffers
    __shared__ float wsum[4];

    const int bid = (int)blockIdx.x;
    const int p   = bid >> 4;        // 0..63
    const int cc  = bid & 15;
    const int r0  = p;               // row tile 0..63
    const int r1  = 127 - p;         // row tile 64..127

    const int nT0 = (cc <= r0) ? (((r0 - cc) >> 4) + 1) : 0;
    const int nT1 = ((r1 - cc) >> 4) + 1;
    const int nS0 = nT0 * 2;
    const int nS  = nS0 + nT1 * 2;

    const int t    = threadIdx.x;
    const int wave = t >> 6;         // 0..3: 32-row group
    const int lane = t & 63;
    const int g    = lane >> 4;      // k-quad
    const int ml   = lane & 15;

    const float m2 = 2.8853900817779268f / (float)(*sigmap);   // 2*log2e/sigma
    const int   SC = 0x7f7f7f7f;     // E8M0 unit scales (2^0)

    // ---- staging invariants: 1024 16B chunks / 256 threads = 4 per thread
    const int gbase = (t >> 4) * 256 + (((t & 15) ^ (t >> 4)) * 16);
    const int lbase = t * 16;

    // ---- bf ds_read bases (col = nt*16 + ml within slice) ----
    int rb0[2], rb1[2];
#pragma unroll
    for (int kc = 0; kc < 2; ++kc) {
        rb0[kc] = ml * 256 + (((kc * 8 + g * 2)     ^ ml) * 16);
        rb1[kc] = ml * 256 + (((kc * 8 + g * 2 + 1) ^ ml) * 16);
    }

    // ---- A-panel registers (reloaded at row switch) ----
    i32x8 af[2][2];
    float a_i[2][4];
    auto loadA = [&](int rowTile) {
        const int rowBase = rowTile * 128;
#pragma unroll
        for (int mt = 0; mt < 2; ++mt) {
            const unsigned char* rp =
                Zf8 + (size_t)(rowBase + wave * 32 + mt * 16 + ml) * 256 + g * 32;
#pragma unroll
            for (int kc = 0; kc < 2; ++kc) {
                union { i32x4 h[2]; i32x8 v; } u;
                u.h[0] = *(const i32x4*)(rp + kc * 128);
                u.h[1] = *(const i32x4*)(rp + kc * 128 + 16);
                af[mt][kc] = u.v;
            }
        }
#pragma unroll
        for (int mt = 0; mt < 2; ++mt)
#pragma unroll
            for (int rr = 0; rr < 4; ++rr)
                a_i[mt][rr] = n2[rowBase + wave * 32 + mt * 16 + g * 4 + rr];
    };

    const int firstRow = nT0 ? r0 : r1;
    loadA(firstRow);
    int curRow = firstRow;

    const f32x4 zacc = {0.0f, 0.0f, 0.0f, 0.0f};

    // slice s -> (rowTile, bc, h); colBase = bc*128 + h*64
    auto sliceCol = [&](int s, int& rowT, int& bc, int& h) {
        int si;
        if (s < nS0) { rowT = r0; si = s; }
        else         { rowT = r1; si = s - nS0; }
        bc = cc + (si >> 2) * 16 * 2;  // unused form; corrected below
        bc = cc + ((si >> 1) * 16);
        h  = si & 1;
    };

    // ---- prologue: stage slice 0 ----
    {
        int rT, bc, h; sliceCol(0, rT, bc, h);
        const unsigned char* sb = Zf8 + (size_t)(bc * 128 + h * 64) * 256 + gbase;
#pragma unroll
        for (int i = 0; i < 4; ++i)
            __builtin_amdgcn_global_load_lds((const AS1 void*)(sb + i * 4096),
                                             (AS3 void*)(smem_b + i * 4096 + lbase), 16, 0, 0);
    }

    float block_acc = 0.0f;
    int cur = 0;

    for (int s = 0; s < nS; ++s) {
        int rowT, bc, h;
        sliceCol(s, rowT, bc, h);
        if (rowT != curRow) { loadA(rowT); curRow = rowT; }   // once per block
        const int colBase = bc * 128 + h * 64;

        // per-slice multiplicative column factors
        float eb[4];
#pragma unroll
        for (int nt = 0; nt < 4; ++nt)
            eb[nt] = __builtin_amdgcn_exp2f(n2[colBase + nt * 16 + ml]);

        __syncthreads();             // slice s staged in buf cur; cur^1 free

        // ---- stage next slice into the other buffer (overlaps compute) ----
        if (s + 1 < nS) {
            int rTN, bcN, hN;
            sliceCol(s + 1, rTN, bcN, hN);
            const unsigned char* sb =
                Zf8 + (size_t)(bcN * 128 + hN * 64) * 256 + gbase;
            char* dst = smem_b + (cur ^ 1) * 16384;
#pragma unroll
            for (int i = 0; i < 4; ++i)
                __builtin_amdgcn_global_load_lds((const AS1 void*)(sb + i * 4096),
                                                 (AS3 void*)(dst + i * 4096 + lbase), 16, 0, 0);
        }

        // ---- compute: 4 nt x (2 mt x 2 kc) MFMA, full-K per slice ----
        const char* buf = smem_b + cur * 16384;
        f32x4 acc[2][4];
#pragma unroll
        for (int nt = 0; nt < 4; ++nt) {
#pragma unroll
            for (int kc = 0; kc < 2; ++kc) {
                union { i32x4 hh[2]; i32x8 v; } u;
                u.hh[0] = *(const i32x4*)(buf + nt * 4096 + rb0[kc]);
                u.hh[1] = *(const i32x4*)(buf + nt * 4096 + rb1[kc]);
                const i32x8 bf = u.v;
#pragma unroll
                for (int mt = 0; mt < 2; ++mt)
                    acc[mt][nt] = __builtin_amdgcn_mfma_scale_f32_16x16x128_f8f6f4(
                        af[mt][kc], bf, (kc == 0) ? zacc : acc[mt][nt],
                        0, 0, 0, SC, 0, SC);
            }
        }

        // ---- epilogue for this slice ----
        float ts0 = 0.0f, ts1 = 0.0f, ts2 = 0.0f, ts3 = 0.0f;
#pragma unroll
        for (int mt = 0; mt < 2; ++mt)
#pragma unroll
            for (int nt = 0; nt < 4; ++nt) {
                const float e = eb[nt];
                ts0 = fmaf(__builtin_amdgcn_exp2f(fmaf(acc[mt][nt][0], m2, a_i[mt][0])), e, ts0);
                ts1 = fmaf(__builtin_amdgcn_exp2f(fmaf(acc[mt][nt][1], m2, a_i[mt][1])), e, ts1);
                ts2 = fmaf(__builtin_amdgcn_exp2f(fmaf(acc[mt][nt][2], m2, a_i[mt][2])), e, ts2);
                ts3 = fmaf(__builtin_amdgcn_exp2f(fmaf(acc[mt][nt][3], m2, a_i[mt][3])), e, ts3);
            }
        const float tsum = (ts0 + ts1) + (ts2 + ts3);

        const float sgn = ((bc < 64) == (rowT < 64)) ? 1.0f : -1.0f;
        const float w   = (bc == rowT) ? sgn : 2.0f * sgn;   // symmetry weight
        block_acc = fmaf(w, tsum, block_acc);
        cur ^= 1;
    }

    // ---- block reduction + hashed atomic ----
    float s = block_acc;
#pragma unroll
    for (int off = 32; off; off >>= 1) s += __shfl_down(s, off, 64);
    if (lane == 0) wsum[wave] = s;
    __syncthreads();
    if (t == 0)
        atomicAdd(part + (bid & 63), wsum[0] + wsum[1] + wsum[2] + wsum[3]);
}

// ---------------------------------------------------------------------------
// Finish: reduce 64 partials, scale, write scalar output.
// ---------------------------------------------------------------------------
__global__ __launch_bounds__(64) void mmd_finish(const float* __restrict__ part,
                                                 float* __restrict__ out) {
    const int lane = threadIdx.x & 63;
    float s = part[lane];
#pragma unroll
    for (int off = 32; off; off >>= 1) s += __shfl_down(s, off, 64);
    if (lane == 0) out[0] = s * (1.0f / 67108864.0f);
}

// ---------------------------------------------------------------------------
extern "C" void kernel_launch(void* const* d_in, const int* in_sizes, int n_in,
                              void* d_out, int out_size, void* d_ws, size_t ws_size,
                              hipStream_t stream) {
    const float* X      = (const float*)d_in[0];
    const float* Y      = (const float*)d_in[1];
    const int*   sigmap = (const int*)d_in[2];
    float*       out    = (float*)d_out;

    unsigned char* Zf8  = (unsigned char*)d_ws;                       // 4 MB
    float*         n2   = (float*)((char*)d_ws + (size_t)TWO_N * DIM);
    float*         part = n2 + TWO_N;                                 // 64 floats

    mmd_prep<<<TWO_N / 4, 256, 0, stream>>>(X, Y, sigmap, Zf8, n2, part);
    mmd_main<<<64 * 16, 256, 0, stream>>>(Zf8, n2, sigmap, part);
    mmd_finish<<<1, 64, 0, stream>>>(part, out);
}